// Round 9
// baseline (81.179 us; speedup 1.0000x reference)
//
#include <hip/hip_runtime.h>
#include <math.h>

#define CIN  64
#define HH   32
#define WW   32
#define OCH  64
#define IKK  576
#define DH   32
#define OIKK 36864
#define NTS  512

struct TsSmem {
    float patch[4][584];      // row stride 584 (2336B, 16B-mult)
    float red[8][8][4][4];    // [kq][jg][jj][pg]
    float spart[4][64];
};
struct OutSmem {
    float xs[CIN][3][36];     // left-pad: xs[ci][kh][1+i]=x[i]
    float tl[DH][36];         // [j][px]
    float hl[16][33];
    float sl[32];
    float psum[2560];         // [tid][10] padded
};
union Smem { TsSmem ts; OutSmem ot; };   // 44.7 KB (out role dominates)

__device__ __forceinline__ float silu_f(float v) {
    return v / (1.0f + __expf(-v));
}

// Fused: blocks 0..511 produce t[b,j,p], s[b,p]; blocks 512..767 consume.
// Handoff: device-scope release (threadfence+atomicAdd) / acquire (spin) flag.
// Deadlock-free: LDS 44.7KB + launch_bounds(256,2) -> >=2 blocks/CU ->
// >=512 co-resident slots; only 256 consumer blocks can spin.
__global__ __launch_bounds__(256, 2) void k_fused(
    const float* __restrict__ x, const float* __restrict__ c,
    const float* __restrict__ kern, const float* __restrict__ bias,
    const float* __restrict__ w1, const float* __restrict__ b1,
    const float* __restrict__ w2, const float* __restrict__ b2,
    float* __restrict__ t_ws, float* __restrict__ s_ws,
    unsigned int* __restrict__ flag, float* __restrict__ out)
{
    __shared__ Smem sm;
    int tid = threadIdx.x;
    int bid = blockIdx.x;

    if (bid < NTS) {
        // ================= ts role: t,s for 4 pixels p=(ph*4+pg)*64+q ======
        int b   = bid >> 8;
        int q   = (bid >> 2) & 63;
        int ph  = bid & 3;
        int par = q >> 5, xq = q & 31;

        for (int idx = tid; idx < 4 * IKK; idx += 256) {
            int pgi = idx / IKK;
            int ikk = idx - pgi * IKK;
            int ci  = ikk / 9;
            int r   = ikk - ci * 9;
            int kh  = r / 3;
            int kw  = r - kh * 3;
            int yy  = 2 * (ph * 4 + pgi) + par + kh - 1;
            int xx  = xq + kw - 1;
            float v = 0.0f;
            if (yy >= 0 && yy < HH && xx >= 0 && xx < WW)
                v = x[((b * CIN + ci) * HH + yy) * WW + xx];
            sm.ts.patch[pgi][ikk] = v;
        }
        __syncthreads();

        int kq = tid >> 5;          // 0..7 (8-way K-split, 72 floats)
        int jg = (tid >> 2) & 7;    // 0..7 -> j = jg*4+jj
        int pg = tid & 3;           // 0..3
        const float4* pr  = (const float4*)(&sm.ts.patch[pg][0]) + kq * 18;
        const float4* wp0 = (const float4*)(w2 + (size_t)(jg * 4 + 0) * OIKK + q * IKK) + kq * 18;
        const float4* wp1 = (const float4*)(w2 + (size_t)(jg * 4 + 1) * OIKK + q * IKK) + kq * 18;
        const float4* wp2 = (const float4*)(w2 + (size_t)(jg * 4 + 2) * OIKK + q * IKK) + kq * 18;
        const float4* wp3 = (const float4*)(w2 + (size_t)(jg * 4 + 3) * OIKK + q * IKK) + kq * 18;
        float4 a0 = {0,0,0,0}, a1 = {0,0,0,0}, a2 = {0,0,0,0}, a3 = {0,0,0,0};
        #pragma unroll 6
        for (int it = 0; it < 18; ++it) {
            float4 pv = pr[it];
            float4 w0 = wp0[it], w1v = wp1[it], w2v = wp2[it], w3v = wp3[it];
            a0.x = fmaf(w0.x, pv.x, a0.x); a0.y = fmaf(w0.y, pv.y, a0.y);
            a0.z = fmaf(w0.z, pv.z, a0.z); a0.w = fmaf(w0.w, pv.w, a0.w);
            a1.x = fmaf(w1v.x, pv.x, a1.x); a1.y = fmaf(w1v.y, pv.y, a1.y);
            a1.z = fmaf(w1v.z, pv.z, a1.z); a1.w = fmaf(w1v.w, pv.w, a1.w);
            a2.x = fmaf(w2v.x, pv.x, a2.x); a2.y = fmaf(w2v.y, pv.y, a2.y);
            a2.z = fmaf(w2v.z, pv.z, a2.z); a2.w = fmaf(w2v.w, pv.w, a2.w);
            a3.x = fmaf(w3v.x, pv.x, a3.x); a3.y = fmaf(w3v.y, pv.y, a3.y);
            a3.z = fmaf(w3v.z, pv.z, a3.z); a3.w = fmaf(w3v.w, pv.w, a3.w);
        }
        sm.ts.red[kq][jg][0][pg] = (a0.x + a0.y) + (a0.z + a0.w);
        sm.ts.red[kq][jg][1][pg] = (a1.x + a1.y) + (a1.z + a1.w);
        sm.ts.red[kq][jg][2][pg] = (a2.x + a2.y) + (a2.z + a2.w);
        sm.ts.red[kq][jg][3][pg] = (a3.x + a3.y) + (a3.z + a3.w);

        {   // s partials: (pix4 x kc64), 9 elems each
            int pix = tid >> 6, kc = tid & 63;
            const float* b2q = b2 + q * IKK + kc * 9;
            const float* pp  = &sm.ts.patch[pix][kc * 9];
            float acc = 0.f;
            #pragma unroll
            for (int i2 = 0; i2 < 9; ++i2) acc = fmaf(pp[i2], b2q[i2], acc);
            sm.ts.spart[pix][kc] = acc;
        }
        __syncthreads();

        if (tid < 128) {
            int j = tid >> 2, pg2 = tid & 3;
            int jg2 = j >> 2, jj2 = j & 3;
            float sum = 0.f;
            #pragma unroll
            for (int k = 0; k < 8; ++k) sum += sm.ts.red[k][jg2][jj2][pg2];
            int p = ((ph << 2) + pg2) * 64 + q;
            t_ws[(size_t)b * 32768 + (size_t)j * 1024 + p] = sum;
        }
        if (tid < 4) {
            float acc = 0.f;
            #pragma unroll
            for (int kc = 0; kc < 64; ++kc) acc += sm.ts.spart[tid][kc];
            s_ws[(b << 10) + ((ph << 2) + tid) * 64 + q] = acc;
        }
        __syncthreads();
        if (tid == 0) {
            __threadfence();   // device-scope release of t_ws/s_ws
            __hip_atomic_fetch_add(flag, 1u, __ATOMIC_RELEASE, __HIP_MEMORY_SCOPE_AGENT);
        }
    } else {
        // ================= out role: 16 o x 32 px (one row) =================
        int obid = bid - NTS;
        int b   = obid >> 7;
        int y   = (obid >> 2) & 31;
        int oc  = obid & 3;

        // xs staging (no t dependency)
        if (tid < 192) {
            int ci = tid / 3;
            int kh = tid - ci * 3;
            int yy = y + kh - 1;
            float4* dst = (float4*)(&sm.ot.xs[ci][kh][0]);
            if (yy >= 0 && yy < HH) {
                const float4* src = (const float4*)(x + ((b * CIN + ci) * HH + yy) * WW);
                float4 v[8];
                #pragma unroll
                for (int j = 0; j < 8; ++j) v[j] = src[j];
                dst[0] = make_float4(0.f, v[0].x, v[0].y, v[0].z);
                #pragma unroll
                for (int j = 1; j < 8; ++j)
                    dst[j] = make_float4(v[j - 1].w, v[j].x, v[j].y, v[j].z);
                dst[8] = make_float4(v[7].w, 0.f, 0.f, 0.f);
            } else {
                float4 z = {0.f, 0.f, 0.f, 0.f};
                #pragma unroll
                for (int j = 0; j < 9; ++j) dst[j] = z;
            }
        }
        // hl: inline MLP (no t dependency)
        for (int idx = tid; idx < 512; idx += 256) {
            int olx = idx >> 5, j = idx & 31;
            int o   = (oc << 4) + olx;
            int pm  = (o << 4) + (y >> 1);
            float f0 = (float)(pm >> 5) * (1.0f / 32.0f);
            float f1 = (float)(pm & 31) * (1.0f / 32.0f);
            float acc = b1[j];
            acc = fmaf(f0, w1[j], acc);
            acc = fmaf(f1, w1[DH + j], acc);
            #pragma unroll
            for (int i = 0; i < 8; ++i)
                acc = fmaf(c[(b << 3) + i], w1[(2 + i) * DH + j], acc);
            sm.ot.hl[olx][j] = silu_f(acc);
        }
        __syncthreads();

        // ---- Phase A: conv partials (overlaps producer blocks) ----
        {
            int cq = tid >> 6;         // 0..3
            int ol = (tid >> 3) & 7;   // 0..7
            int xg = tid & 7;          // 0..7 -> px 4xg..4xg+3
            int o0 = (oc << 4) + ol;
            int o1 = o0 + 8;
            int ci0 = cq << 4;
            const float4* k0p = (const float4*)(kern + o0 * IKK + ci0 * 9);
            const float4* k1p = (const float4*)(kern + o1 * IKK + ci0 * 9);
            float aA[4] = {0.f, 0.f, 0.f, 0.f};
            float aB[4] = {0.f, 0.f, 0.f, 0.f};
            for (int c4 = 0; c4 < 4; ++c4) {
                float ka[36], kb[36];
                #pragma unroll
                for (int rr = 0; rr < 9; ++rr) {
                    float4 va = k0p[c4 * 9 + rr];
                    ka[rr * 4 + 0] = va.x; ka[rr * 4 + 1] = va.y;
                    ka[rr * 4 + 2] = va.z; ka[rr * 4 + 3] = va.w;
                    float4 vb = k1p[c4 * 9 + rr];
                    kb[rr * 4 + 0] = vb.x; kb[rr * 4 + 1] = vb.y;
                    kb[rr * 4 + 2] = vb.z; kb[rr * 4 + 3] = vb.w;
                }
                #pragma unroll
                for (int i = 0; i < 4; ++i) {
                    int ci = ci0 + (c4 << 2) + i;
                    #pragma unroll
                    for (int kh = 0; kh < 3; ++kh) {
                        const float* row = &sm.ot.xs[ci][kh][0];
                        float4 v4 = *(const float4*)(row + 4 * xg);
                        float2 v2 = *(const float2*)(row + 4 * xg + 4);
                        int e = i * 9 + kh * 3;
                        float k0a = ka[e], k1a = ka[e + 1], k2a = ka[e + 2];
                        float k0b = kb[e], k1b = kb[e + 1], k2b = kb[e + 2];
                        aA[0] = fmaf(k0a, v4.x, aA[0]); aA[0] = fmaf(k1a, v4.y, aA[0]); aA[0] = fmaf(k2a, v4.z, aA[0]);
                        aA[1] = fmaf(k0a, v4.y, aA[1]); aA[1] = fmaf(k1a, v4.z, aA[1]); aA[1] = fmaf(k2a, v4.w, aA[1]);
                        aA[2] = fmaf(k0a, v4.z, aA[2]); aA[2] = fmaf(k1a, v4.w, aA[2]); aA[2] = fmaf(k2a, v2.x, aA[2]);
                        aA[3] = fmaf(k0a, v4.w, aA[3]); aA[3] = fmaf(k1a, v2.x, aA[3]); aA[3] = fmaf(k2a, v2.y, aA[3]);
                        aB[0] = fmaf(k0b, v4.x, aB[0]); aB[0] = fmaf(k1b, v4.y, aB[0]); aB[0] = fmaf(k2b, v4.z, aB[0]);
                        aB[1] = fmaf(k0b, v4.y, aB[1]); aB[1] = fmaf(k1b, v4.z, aB[1]); aB[1] = fmaf(k2b, v4.w, aB[1]);
                        aB[2] = fmaf(k0b, v4.z, aB[2]); aB[2] = fmaf(k1b, v4.w, aB[2]); aB[2] = fmaf(k2b, v2.x, aB[2]);
                        aB[3] = fmaf(k0b, v4.w, aB[3]); aB[3] = fmaf(k1b, v2.x, aB[3]); aB[3] = fmaf(k2b, v2.y, aB[3]);
                    }
                }
            }
            float2* sp = (float2*)(sm.ot.psum + tid * 10);
            sp[0] = make_float2(aA[0], aA[1]);
            sp[1] = make_float2(aA[2], aA[3]);
            sp[2] = make_float2(aB[0], aB[1]);
            sp[3] = make_float2(aB[2], aB[3]);
        }

        // ---- wait for producers (acquire), then stage tl/sl ----
        if (tid == 0) {
            while (__hip_atomic_load(flag, __ATOMIC_ACQUIRE, __HIP_MEMORY_SCOPE_AGENT) < NTS)
                __builtin_amdgcn_s_sleep(1);
        }
        __syncthreads();

        {
            int j = tid >> 3, g = tid & 7;
            float4 v = *(const float4*)(t_ws + (size_t)b * 32768 + (size_t)j * 1024 + (y << 5) + (g << 2));
            *(float4*)(&sm.ot.tl[j][g << 2]) = v;
        }
        if (tid < 32) sm.ot.sl[tid] = s_ws[(b << 10) + (y << 5) + tid];
        __syncthreads();

        // ---- Phase B: gather + dynamic part + write ----
        {
            int ou = tid >> 4;   // 0..15
            int xp = tid & 15;   // px pair 2xp, 2xp+1
            int o  = (oc << 4) + ou;
            int ol2 = ou & 7, oo = ou >> 3, xg2 = xp >> 1;
            int ppb = (xp & 1) << 1;
            float c0 = 0.f, c1 = 0.f;
            #pragma unroll
            for (int cq = 0; cq < 4; ++cq) {
                int t2 = (cq << 6) + (ol2 << 3) + xg2;
                float2 v = *(const float2*)(sm.ot.psum + t2 * 10 + (oo << 2) + ppb);
                c0 += v.x; c1 += v.y;
            }
            #pragma unroll 8
            for (int jj = 0; jj < DH; ++jj) {
                float2 tv = *(const float2*)(&sm.ot.tl[jj][2 * xp]);
                float hv = sm.ot.hl[ou][jj];
                c0 = fmaf(hv, tv.x, c0);
                c1 = fmaf(hv, tv.y, c1);
            }
            float bo = bias[o];
            int base = ((b * OCH + o) << 10) + (y << 5) + 2 * xp;
            *(float2*)(out + base) = make_float2(c0 + bo + sm.ot.sl[2 * xp],
                                                 c1 + bo + sm.ot.sl[2 * xp + 1]);
        }
    }
}

extern "C" void kernel_launch(void* const* d_in, const int* in_sizes, int n_in,
                              void* d_out, int out_size, void* d_ws, size_t ws_size,
                              hipStream_t stream) {
    const float* x    = (const float*)d_in[0];
    const float* c    = (const float*)d_in[1];
    const float* kern = (const float*)d_in[2];
    const float* bias = (const float*)d_in[3];
    const float* w1   = (const float*)d_in[4];
    const float* b1   = (const float*)d_in[5];
    const float* w2   = (const float*)d_in[6];
    const float* b2   = (const float*)d_in[7];
    float* out  = (float*)d_out;
    float* t_ws = (float*)d_ws;                       // 65536 floats, [b][j][p]
    float* s_ws = t_ws + 65536;                       // 2048 floats,  [b][p]
    unsigned int* flag = (unsigned int*)(s_ws + 2048);

    hipMemsetAsync((void*)flag, 0, 4, stream);
    k_fused<<<768, 256, 0, stream>>>(x, c, kern, bias, w1, b1, w2, b2,
                                     t_ws, s_ws, flag, out);
}

// Round 10
// 28.510 us; speedup vs baseline: 2.8474x; 2.8474x over previous
//
#include <hip/hip_runtime.h>
#include <math.h>

#define CIN  64
#define HH   32
#define WW   32
#define OCH  64
#define IKK  576
#define DH   32
#define OIKK 36864
#define NB_CONV 256   // conv-role blocks (b,y,oc)

struct TsSmem {
    float patch[4][584];      // [pix][ikk], stride 584
    float red[8][8][4][4];    // [kq][jg][jj][pg]
    float spart[4][64];
    float t_sm[DH][4];        // [j][pg]
    float s_sm[4];
};
struct OutSmem {
    float xs[CIN][3][36];     // left-pad: xs[ci][kh][1+i]=x[i]
    float psum[2560];         // [tid][10] padded
};
union Smem { TsSmem ts; OutSmem ot; };   // ~38 KB (conv role dominates)

__device__ __forceinline__ float silu_f(float v) {
    return v / (1.0f + __expf(-v));
}

// One launch, zero inter-block sync. out zeroed by memset; each element gets
// exactly TWO atomicAdds (conv+bias from a conv-block, dyn+s from a ts-block).
// fp add is commutative -> bit-deterministic across replays.
__global__ __launch_bounds__(256) void k_mono(
    const float* __restrict__ x, const float* __restrict__ c,
    const float* __restrict__ kern, const float* __restrict__ bias,
    const float* __restrict__ w1, const float* __restrict__ b1,
    const float* __restrict__ w2, const float* __restrict__ b2,
    float* __restrict__ out)
{
    __shared__ Smem sm;
    int tid = threadIdx.x;
    int bid = blockIdx.x;

    if (bid < NB_CONV) {
        // ================= conv role: 16 o x 32 px (one row) ================
        int b  = bid >> 7;
        int y  = (bid >> 2) & 31;
        int oc = bid & 3;

        if (tid < 192) {
            int ci = tid / 3;
            int kh = tid - ci * 3;
            int yy = y + kh - 1;
            float4* dst = (float4*)(&sm.ot.xs[ci][kh][0]);
            if (yy >= 0 && yy < HH) {
                const float4* src = (const float4*)(x + ((b * CIN + ci) * HH + yy) * WW);
                float4 v[8];
                #pragma unroll
                for (int j = 0; j < 8; ++j) v[j] = src[j];
                dst[0] = make_float4(0.f, v[0].x, v[0].y, v[0].z);
                #pragma unroll
                for (int j = 1; j < 8; ++j)
                    dst[j] = make_float4(v[j - 1].w, v[j].x, v[j].y, v[j].z);
                dst[8] = make_float4(v[7].w, 0.f, 0.f, 0.f);
            } else {
                float4 z = {0.f, 0.f, 0.f, 0.f};
                #pragma unroll
                for (int j = 0; j < 9; ++j) dst[j] = z;
            }
        }
        __syncthreads();

        // Phase A: conv partials over 16-ci slice
        {
            int cq = tid >> 6;         // 0..3
            int ol = (tid >> 3) & 7;   // 0..7
            int xg = tid & 7;          // 0..7 -> px 4xg..4xg+3
            int o0 = (oc << 4) + ol;
            int o1 = o0 + 8;
            int ci0 = cq << 4;
            const float4* k0p = (const float4*)(kern + o0 * IKK + ci0 * 9);
            const float4* k1p = (const float4*)(kern + o1 * IKK + ci0 * 9);
            float aA[4] = {0.f, 0.f, 0.f, 0.f};
            float aB[4] = {0.f, 0.f, 0.f, 0.f};
            for (int c4 = 0; c4 < 4; ++c4) {
                float ka[36], kb[36];
                #pragma unroll
                for (int rr = 0; rr < 9; ++rr) {
                    float4 va = k0p[c4 * 9 + rr];
                    ka[rr * 4 + 0] = va.x; ka[rr * 4 + 1] = va.y;
                    ka[rr * 4 + 2] = va.z; ka[rr * 4 + 3] = va.w;
                    float4 vb = k1p[c4 * 9 + rr];
                    kb[rr * 4 + 0] = vb.x; kb[rr * 4 + 1] = vb.y;
                    kb[rr * 4 + 2] = vb.z; kb[rr * 4 + 3] = vb.w;
                }
                #pragma unroll
                for (int i = 0; i < 4; ++i) {
                    int ci = ci0 + (c4 << 2) + i;
                    #pragma unroll
                    for (int kh = 0; kh < 3; ++kh) {
                        const float* row = &sm.ot.xs[ci][kh][0];
                        float4 v4 = *(const float4*)(row + 4 * xg);
                        float2 v2 = *(const float2*)(row + 4 * xg + 4);
                        int e = i * 9 + kh * 3;
                        float k0a = ka[e], k1a = ka[e + 1], k2a = ka[e + 2];
                        float k0b = kb[e], k1b = kb[e + 1], k2b = kb[e + 2];
                        aA[0] = fmaf(k0a, v4.x, aA[0]); aA[0] = fmaf(k1a, v4.y, aA[0]); aA[0] = fmaf(k2a, v4.z, aA[0]);
                        aA[1] = fmaf(k0a, v4.y, aA[1]); aA[1] = fmaf(k1a, v4.z, aA[1]); aA[1] = fmaf(k2a, v4.w, aA[1]);
                        aA[2] = fmaf(k0a, v4.z, aA[2]); aA[2] = fmaf(k1a, v4.w, aA[2]); aA[2] = fmaf(k2a, v2.x, aA[2]);
                        aA[3] = fmaf(k0a, v4.w, aA[3]); aA[3] = fmaf(k1a, v2.x, aA[3]); aA[3] = fmaf(k2a, v2.y, aA[3]);
                        aB[0] = fmaf(k0b, v4.x, aB[0]); aB[0] = fmaf(k1b, v4.y, aB[0]); aB[0] = fmaf(k2b, v4.z, aB[0]);
                        aB[1] = fmaf(k0b, v4.y, aB[1]); aB[1] = fmaf(k1b, v4.z, aB[1]); aB[1] = fmaf(k2b, v4.w, aB[1]);
                        aB[2] = fmaf(k0b, v4.z, aB[2]); aB[2] = fmaf(k1b, v4.w, aB[2]); aB[2] = fmaf(k2b, v2.x, aB[2]);
                        aB[3] = fmaf(k0b, v4.w, aB[3]); aB[3] = fmaf(k1b, v2.x, aB[3]); aB[3] = fmaf(k2b, v2.y, aB[3]);
                    }
                }
            }
            float2* sp = (float2*)(sm.ot.psum + tid * 10);
            sp[0] = make_float2(aA[0], aA[1]);
            sp[1] = make_float2(aA[2], aA[3]);
            sp[2] = make_float2(aB[0], aB[1]);
            sp[3] = make_float2(aB[2], aB[3]);
        }
        __syncthreads();

        // Phase B: gather over cq + bias -> atomicAdd
        {
            int ou = tid >> 4;   // 0..15
            int xp = tid & 15;   // px pair 2xp, 2xp+1
            int o  = (oc << 4) + ou;
            int ol2 = ou & 7, oo = ou >> 3, xg2 = xp >> 1;
            int ppb = (xp & 1) << 1;
            float c0 = 0.f, c1 = 0.f;
            #pragma unroll
            for (int cq = 0; cq < 4; ++cq) {
                int t2 = (cq << 6) + (ol2 << 3) + xg2;
                float2 v = *(const float2*)(sm.ot.psum + t2 * 10 + (oo << 2) + ppb);
                c0 += v.x; c1 += v.y;
            }
            float bo = bias[o];
            int base = ((b * OCH + o) << 10) + (y << 5) + 2 * xp;
            atomicAdd(&out[base],     c0 + bo);
            atomicAdd(&out[base + 1], c1 + bo);
        }
    } else {
        // ====== ts role: t,s for 4 pixels p=(ph*4+pg)*64+q, then dyn ========
        int obid = bid - NB_CONV;
        int b   = obid >> 8;
        int q   = (obid >> 2) & 63;
        int ph  = obid & 3;
        int par = q >> 5, xq = q & 31;

        for (int idx = tid; idx < 4 * IKK; idx += 256) {
            int pgi = idx / IKK;
            int ikk = idx - pgi * IKK;
            int ci  = ikk / 9;
            int r   = ikk - ci * 9;
            int kh  = r / 3;
            int kw  = r - kh * 3;
            int yy  = 2 * (ph * 4 + pgi) + par + kh - 1;
            int xx  = xq + kw - 1;
            float v = 0.0f;
            if (yy >= 0 && yy < HH && xx >= 0 && xx < WW)
                v = x[((b * CIN + ci) * HH + yy) * WW + xx];
            sm.ts.patch[pgi][ikk] = v;
        }
        __syncthreads();

        int kq = tid >> 5;          // 0..7 (8-way K-split, 72 floats)
        int jg = (tid >> 2) & 7;    // 0..7 -> j = jg*4+jj
        int pg = tid & 3;           // 0..3
        const float4* pr  = (const float4*)(&sm.ts.patch[pg][0]) + kq * 18;
        const float4* wp0 = (const float4*)(w2 + (size_t)(jg * 4 + 0) * OIKK + q * IKK) + kq * 18;
        const float4* wp1 = (const float4*)(w2 + (size_t)(jg * 4 + 1) * OIKK + q * IKK) + kq * 18;
        const float4* wp2 = (const float4*)(w2 + (size_t)(jg * 4 + 2) * OIKK + q * IKK) + kq * 18;
        const float4* wp3 = (const float4*)(w2 + (size_t)(jg * 4 + 3) * OIKK + q * IKK) + kq * 18;
        float4 a0 = {0,0,0,0}, a1 = {0,0,0,0}, a2 = {0,0,0,0}, a3 = {0,0,0,0};
        #pragma unroll 6
        for (int it = 0; it < 18; ++it) {
            float4 pv = pr[it];
            float4 w0 = wp0[it], w1v = wp1[it], w2v = wp2[it], w3v = wp3[it];
            a0.x = fmaf(w0.x, pv.x, a0.x); a0.y = fmaf(w0.y, pv.y, a0.y);
            a0.z = fmaf(w0.z, pv.z, a0.z); a0.w = fmaf(w0.w, pv.w, a0.w);
            a1.x = fmaf(w1v.x, pv.x, a1.x); a1.y = fmaf(w1v.y, pv.y, a1.y);
            a1.z = fmaf(w1v.z, pv.z, a1.z); a1.w = fmaf(w1v.w, pv.w, a1.w);
            a2.x = fmaf(w2v.x, pv.x, a2.x); a2.y = fmaf(w2v.y, pv.y, a2.y);
            a2.z = fmaf(w2v.z, pv.z, a2.z); a2.w = fmaf(w2v.w, pv.w, a2.w);
            a3.x = fmaf(w3v.x, pv.x, a3.x); a3.y = fmaf(w3v.y, pv.y, a3.y);
            a3.z = fmaf(w3v.z, pv.z, a3.z); a3.w = fmaf(w3v.w, pv.w, a3.w);
        }
        sm.ts.red[kq][jg][0][pg] = (a0.x + a0.y) + (a0.z + a0.w);
        sm.ts.red[kq][jg][1][pg] = (a1.x + a1.y) + (a1.z + a1.w);
        sm.ts.red[kq][jg][2][pg] = (a2.x + a2.y) + (a2.z + a2.w);
        sm.ts.red[kq][jg][3][pg] = (a3.x + a3.y) + (a3.z + a3.w);

        {   // s partials: (pix4 x kc64), 9 elems each
            int pix = tid >> 6, kc = tid & 63;
            const float* b2q = b2 + q * IKK + kc * 9;
            const float* pp  = &sm.ts.patch[pix][kc * 9];
            float acc = 0.f;
            #pragma unroll
            for (int i2 = 0; i2 < 9; ++i2) acc = fmaf(pp[i2], b2q[i2], acc);
            sm.ts.spart[pix][kc] = acc;
        }
        __syncthreads();

        if (tid < 128) {           // t reduce over kq -> t_sm[j][pg]
            int j = tid >> 2, pg2 = tid & 3;
            int jg2 = j >> 2, jj2 = j & 3;
            float sum = 0.f;
            #pragma unroll
            for (int k = 0; k < 8; ++k) sum += sm.ts.red[k][jg2][jj2][pg2];
            sm.ts.t_sm[j][pg2] = sum;
        }
        if (tid < 4) {             // s reduce -> s_sm[pg]
            float acc = 0.f;
            #pragma unroll
            for (int kc = 0; kc < 64; ++kc) acc += sm.ts.spart[tid][kc];
            sm.ts.s_sm[tid] = acc;
        }
        __syncthreads();

        // dyn epilogue: thread = (o, pgl); h recomputed inline (1:1 with pm)
        {
            int o   = tid >> 2;    // 0..63
            int pgl = tid & 3;
            int pp  = (ph << 2) + pgl;
            int pm  = (o << 4) + pp;
            float f0 = (float)(pm >> 5) * (1.0f / 32.0f);
            float f1 = (float)(pm & 31) * (1.0f / 32.0f);
            float cb[8];
            #pragma unroll
            for (int i = 0; i < 8; ++i) cb[i] = c[(b << 3) + i];
            float dyn = sm.ts.s_sm[pgl];
            #pragma unroll 4
            for (int j = 0; j < DH; ++j) {
                float v = b1[j];
                v = fmaf(f0, w1[j], v);
                v = fmaf(f1, w1[DH + j], v);
                #pragma unroll
                for (int i = 0; i < 8; ++i)
                    v = fmaf(cb[i], w1[(2 + i) * DH + j], v);
                dyn = fmaf(silu_f(v), sm.ts.t_sm[j][pgl], dyn);
            }
            int p = (pp << 6) + q;
            atomicAdd(&out[((b * OCH + o) << 10) + p], dyn);
        }
    }
}

extern "C" void kernel_launch(void* const* d_in, const int* in_sizes, int n_in,
                              void* d_out, int out_size, void* d_ws, size_t ws_size,
                              hipStream_t stream) {
    const float* x    = (const float*)d_in[0];
    const float* c    = (const float*)d_in[1];
    const float* kern = (const float*)d_in[2];
    const float* bias = (const float*)d_in[3];
    const float* w1   = (const float*)d_in[4];
    const float* b1   = (const float*)d_in[5];
    const float* w2   = (const float*)d_in[6];
    const float* b2   = (const float*)d_in[7];
    float* out = (float*)d_out;

    hipMemsetAsync(out, 0, (size_t)out_size * sizeof(float), stream);
    k_mono<<<NB_CONV + 512, 256, 0, stream>>>(x, c, kern, bias, w1, b1, w2, b2, out);
}